// Round 2
// baseline (400.631 us; speedup 1.0000x reference)
//
#include <hip/hip_runtime.h>
#include <hip/hip_cooperative_groups.h>

namespace cg = cooperative_groups;

// ---------------------------------------------------------------------------
// GeometricSuperpositionSearch (all fp32): the reference collapses to
//   new[b,n,l] = sum_j x[b,n,j] * comb[b][j^l] * sign(j^l, j)
// where comb[b] is a single 16-component multivector per batch.
//
// R6: fused cooperative kernel (R5 design) + launch-failure fallback to the
// previously harness-verified 3-kernel path. hipLaunchCooperativeKernel's
// return code is checked at capture time; any error -> 3 plain launches.
//
// Fused design:
//  - one dispatch, two grid.sync()s (removes 2 launch boundaries)
//  - same block owns the same 512-row slab in phase 1 (reduce) and phase 3
//    (apply) -> 2nd cpu_state read hits the same XCD's L2
//  - non-zero blocks prefetch their phase-3 rows into registers BEFORE the
//    2nd grid.sync, overlapping block-0's serial MLP/softmax chain
//  - block 0 computes rule-summary + gumbel (no phase-1 deps) before sync 1
// RNG: jax partitionable threefry: counter (0, t), key (0, 42),
// bits = x0 ^ x1.  (Verified in the prior session: absmax 3.9e-3.)
// ---------------------------------------------------------------------------

#define B_ 8
#define N_ 65536
#define D_ 16
#define K_ 8
#define M_ 8
#define HID_ 64
#define BLK_PER_B 128                    // slabs per batch
#define ROWS_PER_BLK (N_ / BLK_PER_B)    // 512 rows -> 2048 float4 per slab
#define GRID_ (B_ * BLK_PER_B)           // 1024 blocks = 4 per CU

// ---- compile-time Cayley sign table: SGN.v[a][b] = sign of e_a * e_b -> e_{a^b}
struct SgnTab { float v[16][16]; };
constexpr SgnTab make_sgn() {
  SgnTab t{};
  for (int a = 0; a < 16; a++)
    for (int b = 0; b < 16; b++) {
      float s = 1.0f;
      for (int i = 0; i < 4; i++)
        if ((b >> i) & 1) {
          int h = a >> (i + 1), pc = 0;
          for (int q = 0; q < 4; q++) pc += (h >> q) & 1;
          if (pc & 1) s = -s;
          if ((a >> i) & 1) s *= (i == 0 ? 0.0f : 1.0f);  // metric {0,1,1,1}
        }
      t.v[a][b] = s;
    }
  return t;
}
constexpr SgnTab SGN = make_sgn();

// ---- threefry2x32-20, exactly as in jax/_src/prng.py ----
__device__ __forceinline__ unsigned rotl32(unsigned x, int n) {
  return (x << n) | (x >> (32 - n));
}
__device__ void threefry2x32(unsigned k0, unsigned k1, unsigned& x0, unsigned& x1) {
  unsigned ks0 = k0, ks1 = k1, ks2 = k0 ^ k1 ^ 0x1BD11BDAu;
  x0 += ks0; x1 += ks1;
  const int rotA[4] = {13, 15, 26, 6};
  const int rotB[4] = {17, 29, 16, 24};
#define TF_R4(rot)                                      \
  _Pragma("unroll")                                     \
  for (int r = 0; r < 4; r++) {                         \
    x0 += x1; x1 = rotl32(x1, rot[r]); x1 ^= x0;        \
  }
  TF_R4(rotA); x0 += ks1; x1 += ks2 + 1u;
  TF_R4(rotB); x0 += ks2; x1 += ks0 + 2u;
  TF_R4(rotA); x0 += ks0; x1 += ks1 + 3u;
  TF_R4(rotB); x0 += ks1; x1 += ks2 + 4u;
  TF_R4(rotA); x0 += ks2; x1 += ks0 + 5u;
#undef TF_R4
}

__device__ __forceinline__ void apply_row(const float cb[16], const float x[16],
                                          float o[16]) {
#pragma unroll
  for (int l = 0; l < 16; l++) {
    float acc = 0.f;
#pragma unroll
    for (int j = 0; j < 16; j++) {
      const float s = SGN.v[j ^ l][j];                  // compile-time constant
      if (s > 0.5f)       acc = fmaf(cb[j ^ l], x[j], acc);
      else if (s < -0.5f) acc = fmaf(-cb[j ^ l], x[j], acc);
    }
    o[l] = acc;
  }
}

// ---------------------------------------------------------------------------
// Small-problem device helpers shared by fused phase 2 and fallback k2.
// All operate on one 256-thread block with the given shared buffers.
// ---------------------------------------------------------------------------
struct K2Shared {
  float summary[8][16], rs[8][16], gn[8][5], h[8][64], sc[8][8];
  float instr[8][8][16], g64[64], wts[8][8];
  float redA[8][16][16];  // [b][seg][d]
};

__device__ void k2_body(K2Shared& S, int t,
                        const float* __restrict__ partial,
                        const float* __restrict__ ctrl,
                        const float* __restrict__ templates,
                        const float* __restrict__ W1,
                        const float* __restrict__ b1,
                        const float* __restrict__ W2,
                        const float* __restrict__ b2,
                        const float* __restrict__ Wr,
                        const float* __restrict__ br,
                        const float* __restrict__ logt,
                        float* __restrict__ comb) {
  // A: reduce partial[8][128][16]. flat idx = c*256+t: b = c>>3, d = t&15.
  {
    float acc[8];
#pragma unroll
    for (int q = 0; q < 8; q++) acc[q] = 0.f;
#pragma unroll
    for (int c = 0; c < 64; c++)
      acc[c >> 3] += partial[c * 256 + t];   // 64 coalesced, independent loads
#pragma unroll
    for (int q = 0; q < 8; q++) S.redA[q][t >> 4][t & 15] = acc[q];
  }
  __syncthreads();
  if (t < 128) {
    const int bb = t >> 4, d = t & 15;
    float s = 0.f;
#pragma unroll
    for (int g = 0; g < 16; g++) s += S.redA[bb][g][d];
    S.summary[bb][d] = s * (1.0f / (float)N_);
  }
  __syncthreads();
  // B: grade norms
  if (t < 40) {
    const int bb = t / 5, g = t % 5;
    float s = 0.f;
    for (int d = 0; d < 16; d++)
      if (__popc(d) == g) { float v = S.summary[bb][d]; s += v * v; }
    S.gn[bb][g] = sqrtf(s + 1e-12f);
  }
  __syncthreads();
  // C1: hidden layer [8][64]
  for (int idx = t; idx < B_ * HID_; idx += 256) {
    const int bb = idx >> 6, j = idx & 63;
    float a = b1[j];
    for (int i = 0; i < 9; i++) {
      float in = (i < 5) ? S.gn[bb][i] : ctrl[bb * 4 + (i - 5)];
      a += in * W1[i * HID_ + j];
    }
    S.h[bb][j] = fmaxf(a, 0.f);
  }
  __syncthreads();
  // C2: scores [8][8]
  if (t < 64) {
    const int bb = t >> 3, k = t & 7;
    float a = b2[k];
    for (int j = 0; j < HID_; j++) a += S.h[bb][j] * W2[j * K_ + k];
    S.sc[bb][k] = a;
  }
  __syncthreads();
  // D: instructions [8][8][16] = scores * (templates + rule_mod)
  for (int idx = t; idx < B_ * K_ * 16; idx += 256) {
    const int bb = idx >> 7, k = (idx >> 4) & 7, d = idx & 15;
    float a = br[k * 16 + d];
    for (int j = 0; j < 16; j++) a += S.rs[bb][j] * Wr[j * 128 + k * 16 + d];
    S.instr[bb][k][d] = S.sc[bb][k] * (templates[k * 16 + d] + a);
  }
  // weights: softmax((scores+g)/tau)
  if (t < 8) {
    float lt = logt[0];
    float tau = fminf(fmaxf(expf(lt), 0.1f), 5.0f);
    float z[8], m = -1e30f;
    for (int k = 0; k < 8; k++) {
      z[k] = (S.sc[t][k] + S.g64[t * 8 + k]) / tau;
      m = fmaxf(m, z[k]);
    }
    float ssum = 0.f;
    for (int k = 0; k < 8; k++) { z[k] = expf(z[k] - m); ssum += z[k]; }
    for (int k = 0; k < 8; k++) S.wts[t][k] = z[k] / ssum;
  }
  __syncthreads();
  // F: comb[b][i] = sum_k w * instr
  if (t < 128) {
    const int bb = t >> 4, i = t & 15;
    float s = 0.f;
    for (int k = 0; k < 8; k++) s += S.wts[bb][k] * S.instr[bb][k][i];
    comb[bb * 16 + i] = s;
  }
}

__device__ __forceinline__ void k2_prelude(K2Shared& S, int t,
                                           const float* __restrict__ rulemem) {
  if (t < 128) {
    const int bb = t >> 4, d = t & 15;
    float rsum = 0.f;
    for (int m = 0; m < M_; m++) rsum += rulemem[(bb * M_ + m) * 16 + d];
    S.rs[bb][d] = rsum * (1.0f / (float)M_);
  }
  if (t < 64) {   // partitionable threefry gumbel: counter (0, t), key (0, 42)
    unsigned x0 = 0u, x1 = (unsigned)t;
    threefry2x32(0u, 42u, x0, x1);
    unsigned bits = x0 ^ x1;
    float f01 = __uint_as_float((bits >> 9) | 0x3f800000u) - 1.0f;
    float u = fmaxf(1e-6f, f01 * (1.0f - 2e-6f) + 1e-6f);
    S.g64[t] = -logf(-logf(u));
  }
}

// ---------------------------------------------------------------------------
// fused cooperative kernel: grid = 1024 x 256  (4 blocks / CU, co-resident)
// ---------------------------------------------------------------------------
__global__ __launch_bounds__(256, 4) void fused(
    const float* __restrict__ cpu,       // [8,65536,16]
    const float* __restrict__ ctrl,      // [8,4]
    const float* __restrict__ rulemem,   // [8,8,16]
    const float* __restrict__ templates, // [8,16]
    const float* __restrict__ W1,        // [9,64]
    const float* __restrict__ b1,        // [64]
    const float* __restrict__ W2,        // [64,8]
    const float* __restrict__ b2,        // [8]
    const float* __restrict__ Wr,        // [16,128]
    const float* __restrict__ br,        // [128]
    const float* __restrict__ logt,      // [1]
    float* __restrict__ partial,         // ws: [8*128*16]
    float* __restrict__ comb,            // ws: [8*16]
    float* __restrict__ out) {           // [8,65536,16]
  cg::grid_group grid = cg::this_grid();
  const int t = threadIdx.x;
  const int bid = blockIdx.x;
  const int b = bid >> 7;            // batch (wave-uniform)
  const int blk = bid & 127;         // slab within batch

  __shared__ float red[256 * 4];
  __shared__ K2Shared S;

  // ---------------- Phase 1: per-slab reduce of cpu_state ----------------
  {
    const float4* base =
        (const float4*)(cpu + (((size_t)b << 16) + (size_t)blk * ROWS_PER_BLK) * D_);
    float a0 = 0.f, a1 = 0.f, a2 = 0.f, a3 = 0.f;
#pragma unroll
    for (int i = 0; i < (ROWS_PER_BLK * 4) / 256; i++) {   // 8 iters
      float4 v = base[i * 256 + t];
      a0 += v.x; a1 += v.y; a2 += v.z; a3 += v.w;
    }
    // thread t holds components d = 4*(t&3)+j (j=0..3)
    red[t * 4 + 0] = a0; red[t * 4 + 1] = a1;
    red[t * 4 + 2] = a2; red[t * 4 + 3] = a3;
    __syncthreads();
    if (t < 16) {
      const int c = t >> 2, j = t & 3;       // component d = 4c + j = t
      float s = 0.f;
#pragma unroll
      for (int m = 0; m < 64; m++) s += red[(c + 4 * m) * 4 + j];
      partial[((size_t)b * BLK_PER_B + blk) * 16 + t] = s;
    }
  }

  // block 0: phase-2 pieces with NO phase-1 dependency (overlap them here)
  if (bid == 0) k2_prelude(S, t, rulemem);

  __threadfence();
  grid.sync();

  // ---------------- Phase 2: block 0 computes comb[8][16] ----------------
  if (bid == 0) {
    k2_body(S, t, partial, ctrl, templates, W1, b1, W2, b2, Wr, br, logt, comb);
    __threadfence();
  }

  // ---------------- Phase 3 prefetch: issue row loads BEFORE waiting ------
  // (reads cpu only -> independent of phase 2; overlaps block-0's chain;
  //  same rows this block reduced in phase 1 -> same-XCD L2 hits)
  const size_t row0 = ((size_t)b << 16) + (size_t)blk * ROWS_PER_BLK + t;
  const float4* p0 = (const float4*)(cpu + row0 * D_);
  const float4* p1 = (const float4*)(cpu + (row0 + 256) * D_);
  float4 u0 = p0[0], u1 = p0[1], u2 = p0[2], u3 = p0[3];
  float4 w0 = p1[0], w1 = p1[1], w2 = p1[2], w3 = p1[3];

  grid.sync();

  // ---------------- Phase 3: apply signed-permutation operator ------------
  float cb[16];
  {
    const float* cp = comb + b * 16;
#pragma unroll
    for (int i = 0; i < 16; i++) cb[i] = cp[i];          // uniform -> s_load
  }

  {
    float x[16] = {u0.x, u0.y, u0.z, u0.w, u1.x, u1.y, u1.z, u1.w,
                   u2.x, u2.y, u2.z, u2.w, u3.x, u3.y, u3.z, u3.w};
    float o[16];
    apply_row(cb, x, o);
    float4* q = (float4*)(out + row0 * D_);
    q[0] = make_float4(o[0],  o[1],  o[2],  o[3]);
    q[1] = make_float4(o[4],  o[5],  o[6],  o[7]);
    q[2] = make_float4(o[8],  o[9],  o[10], o[11]);
    q[3] = make_float4(o[12], o[13], o[14], o[15]);
  }
  {
    float x[16] = {w0.x, w0.y, w0.z, w0.w, w1.x, w1.y, w1.z, w1.w,
                   w2.x, w2.y, w2.z, w2.w, w3.x, w3.y, w3.z, w3.w};
    float o[16];
    apply_row(cb, x, o);
    float4* q = (float4*)(out + (row0 + 256) * D_);
    q[0] = make_float4(o[0],  o[1],  o[2],  o[3]);
    q[1] = make_float4(o[4],  o[5],  o[6],  o[7]);
    q[2] = make_float4(o[8],  o[9],  o[10], o[11]);
    q[3] = make_float4(o[12], o[13], o[14], o[15]);
  }
}

// ---------------------------------------------------------------------------
// Fallback path: previously harness-verified 3-kernel structure (plain
// launches), used only if hipLaunchCooperativeKernel returns an error.
// ---------------------------------------------------------------------------
__global__ __launch_bounds__(256) void k1_reduce(
    const float* __restrict__ cpu, float* __restrict__ partial) {
  const int b = blockIdx.y, blk = blockIdx.x, t = threadIdx.x;
  const float4* base =
      (const float4*)(cpu + (((size_t)b << 16) + (size_t)blk * ROWS_PER_BLK) * D_);
  float a0 = 0.f, a1 = 0.f, a2 = 0.f, a3 = 0.f;
#pragma unroll
  for (int i = 0; i < (ROWS_PER_BLK * 4) / 256; i++) {   // 8 iters
    float4 v = base[i * 256 + t];
    a0 += v.x; a1 += v.y; a2 += v.z; a3 += v.w;
  }
  __shared__ float red[256 * 4];
  red[t * 4 + 0] = a0; red[t * 4 + 1] = a1;
  red[t * 4 + 2] = a2; red[t * 4 + 3] = a3;
  __syncthreads();
  if (t < 16) {
    const int c = t >> 2, j = t & 3;
    float s = 0.f;
#pragma unroll
    for (int m = 0; m < 64; m++) s += red[(c + 4 * m) * 4 + j];
    partial[((size_t)b * BLK_PER_B + blk) * 16 + t] = s;
  }
}

__global__ __launch_bounds__(256) void k2_small(
    const float* __restrict__ partial, const float* __restrict__ ctrl,
    const float* __restrict__ rulemem, const float* __restrict__ templates,
    const float* __restrict__ W1, const float* __restrict__ b1,
    const float* __restrict__ W2, const float* __restrict__ b2,
    const float* __restrict__ Wr, const float* __restrict__ br,
    const float* __restrict__ logt, float* __restrict__ comb) {
  const int t = threadIdx.x;
  __shared__ K2Shared S;
  k2_prelude(S, t, rulemem);
  __syncthreads();
  k2_body(S, t, partial, ctrl, templates, W1, b1, W2, b2, Wr, br, logt, comb);
}

__global__ __launch_bounds__(256) void k3_apply(
    const float* __restrict__ cpu, const float* __restrict__ comb,
    float* __restrict__ out) {
  const int b = blockIdx.x >> 8;                       // wave-uniform
  const int rowInB = ((blockIdx.x & 255) << 8) + threadIdx.x;
  const size_t row = ((size_t)b << 16) + (size_t)rowInB;

  float cb[16];
  const float* cp = comb + b * 16;
#pragma unroll
  for (int i = 0; i < 16; i++) cb[i] = cp[i];

  const float4* p = (const float4*)(cpu + row * D_);
  float4 v0 = p[0], v1 = p[1], v2 = p[2], v3 = p[3];
  float x[16] = {v0.x, v0.y, v0.z, v0.w, v1.x, v1.y, v1.z, v1.w,
                 v2.x, v2.y, v2.z, v2.w, v3.x, v3.y, v3.z, v3.w};
  float o[16];
  apply_row(cb, x, o);
  float4* q = (float4*)(out + row * D_);
  q[0] = make_float4(o[0],  o[1],  o[2],  o[3]);
  q[1] = make_float4(o[4],  o[5],  o[6],  o[7]);
  q[2] = make_float4(o[8],  o[9],  o[10], o[11]);
  q[3] = make_float4(o[12], o[13], o[14], o[15]);
}

extern "C" void kernel_launch(void* const* d_in, const int* in_sizes, int n_in,
                              void* d_out, int out_size, void* d_ws, size_t ws_size,
                              hipStream_t stream) {
  const float* cpu       = (const float*)d_in[0];
  const float* ctrl      = (const float*)d_in[1];
  const float* rulemem   = (const float*)d_in[2];
  const float* templates = (const float*)d_in[3];
  const float* W1        = (const float*)d_in[4];
  const float* b1        = (const float*)d_in[5];
  const float* W2        = (const float*)d_in[6];
  const float* b2        = (const float*)d_in[7];
  const float* Wr        = (const float*)d_in[8];
  const float* br        = (const float*)d_in[9];
  const float* logt      = (const float*)d_in[10];
  float* outp = (float*)d_out;

  // partial: 8*128*16 floats (64 KiB) + comb: 128 floats.
  float* partial = (float*)d_ws;
  float* comb;
  const size_t need = (size_t)(B_ * BLK_PER_B * 16 + B_ * 16) * sizeof(float);
  if (ws_size >= need) {
    comb = partial + (size_t)B_ * BLK_PER_B * 16;
  } else {
    // fallback: stage partial in the output buffer (fully consumed before any
    // phase-3 store; the regions are separated by grid.sync / kernel boundary)
    partial = outp;
    comb = (float*)d_ws;
  }

  void* args[] = {
      (void*)&cpu, (void*)&ctrl, (void*)&rulemem, (void*)&templates,
      (void*)&W1, (void*)&b1, (void*)&W2, (void*)&b2,
      (void*)&Wr, (void*)&br, (void*)&logt,
      (void*)&partial, (void*)&comb, (void*)&outp};
  hipError_t err = hipLaunchCooperativeKernel((void*)fused, dim3(GRID_),
                                              dim3(256), args, 0, stream);
  if (err != hipSuccess) {
    // Previously verified 3-kernel path.
    k1_reduce<<<dim3(BLK_PER_B, B_), 256, 0, stream>>>(cpu, partial);
    k2_small<<<1, 256, 0, stream>>>(partial, ctrl, rulemem, templates, W1, b1,
                                    W2, b2, Wr, br, logt, comb);
    k3_apply<<<2048, 256, 0, stream>>>(cpu, comb, outp);
  }
}

// Round 3
// 118.549 us; speedup vs baseline: 3.3795x; 3.3795x over previous
//
#include <hip/hip_runtime.h>

// ---------------------------------------------------------------------------
// GeometricSuperpositionSearch (all fp32): the reference collapses to
//   new[b,n,l] = sum_j x[b,n,j] * comb[b][j^l] * sign(j^l, j)
// where comb[b] is a single 16-component multivector per batch:
//   comb[b][i] = sum_k weights[b,k] * scores[b,k] * (templates[k,i] + rule_mod[b,k,i])
//
// R7: REVERT cooperative fusion (R6 measured 300 us/dispatch: holding the
// 32-float phase-3 prefetch across grid.sync() spilled ~53 floats/thread to
// scratch -> 55 MB extra WRITE + fills, VALUBusy 1.3%). Back to the verified
// 3-kernel structure; k1 widened to 1024 blocks. Goal this round: per-dispatch
// counters for k1/k2/k3 to target the real bottleneck.
//
// RNG: jax partitionable threefry: element t -> counter (0, t), key (0, 42),
// bits = x0 ^ x1.  (Verified: absmax 3.9e-3.)
// ---------------------------------------------------------------------------

#define B_ 8
#define N_ 65536
#define D_ 16
#define K_ 8
#define M_ 8
#define HID_ 64
#define BLK_PER_B 128                    // k1 slabs per batch
#define ROWS_PER_BLK (N_ / BLK_PER_B)    // 512 rows -> 2048 float4 per slab

// ---- compile-time Cayley sign table: SGN.v[a][b] = sign of e_a * e_b -> e_{a^b}
struct SgnTab { float v[16][16]; };
constexpr SgnTab make_sgn() {
  SgnTab t{};
  for (int a = 0; a < 16; a++)
    for (int b = 0; b < 16; b++) {
      float s = 1.0f;
      for (int i = 0; i < 4; i++)
        if ((b >> i) & 1) {
          int h = a >> (i + 1), pc = 0;
          for (int q = 0; q < 4; q++) pc += (h >> q) & 1;
          if (pc & 1) s = -s;
          if ((a >> i) & 1) s *= (i == 0 ? 0.0f : 1.0f);  // metric {0,1,1,1}
        }
      t.v[a][b] = s;
    }
  return t;
}
constexpr SgnTab SGN = make_sgn();

// ---- threefry2x32-20, exactly as in jax/_src/prng.py ----
__device__ __forceinline__ unsigned rotl32(unsigned x, int n) {
  return (x << n) | (x >> (32 - n));
}
__device__ void threefry2x32(unsigned k0, unsigned k1, unsigned& x0, unsigned& x1) {
  unsigned ks0 = k0, ks1 = k1, ks2 = k0 ^ k1 ^ 0x1BD11BDAu;
  x0 += ks0; x1 += ks1;
  const int rotA[4] = {13, 15, 26, 6};
  const int rotB[4] = {17, 29, 16, 24};
#define TF_R4(rot)                                      \
  _Pragma("unroll")                                     \
  for (int r = 0; r < 4; r++) {                         \
    x0 += x1; x1 = rotl32(x1, rot[r]); x1 ^= x0;        \
  }
  TF_R4(rotA); x0 += ks1; x1 += ks2 + 1u;
  TF_R4(rotB); x0 += ks2; x1 += ks0 + 2u;
  TF_R4(rotA); x0 += ks0; x1 += ks1 + 3u;
  TF_R4(rotB); x0 += ks1; x1 += ks2 + 4u;
  TF_R4(rotA); x0 += ks2; x1 += ks0 + 5u;
#undef TF_R4
}

__device__ __forceinline__ void apply_row(const float cb[16], const float x[16],
                                          float o[16]) {
#pragma unroll
  for (int l = 0; l < 16; l++) {
    float acc = 0.f;
#pragma unroll
    for (int j = 0; j < 16; j++) {
      const float s = SGN.v[j ^ l][j];                  // compile-time constant
      if (s > 0.5f)       acc = fmaf(cb[j ^ l], x[j], acc);
      else if (s < -0.5f) acc = fmaf(-cb[j ^ l], x[j], acc);
    }
    o[l] = acc;
  }
}

// ---------------------------------------------------------------------------
// k1: per-(b,d) partial sums of cpu_state over a 512-row slab.
// grid (BLK_PER_B, B_) = 1024 blocks, 256 threads.
// thread t owns component group 4*(t&3)..+3 of its float4 lane.
// ---------------------------------------------------------------------------
__global__ __launch_bounds__(256) void k1_reduce(
    const float* __restrict__ cpu, float* __restrict__ partial) {
  const int b = blockIdx.y, blk = blockIdx.x, t = threadIdx.x;
  const float4* base =
      (const float4*)(cpu + (((size_t)b << 16) + (size_t)blk * ROWS_PER_BLK) * D_);
  float a0 = 0.f, a1 = 0.f, a2 = 0.f, a3 = 0.f;
#pragma unroll
  for (int i = 0; i < (ROWS_PER_BLK * 4) / 256; i++) {   // 8 iters
    float4 v = base[i * 256 + t];
    a0 += v.x; a1 += v.y; a2 += v.z; a3 += v.w;
  }
  __shared__ float red[256 * 4];
  red[t * 4 + 0] = a0; red[t * 4 + 1] = a1;
  red[t * 4 + 2] = a2; red[t * 4 + 3] = a3;
  __syncthreads();
  if (t < 16) {
    const int c = t >> 2, j = t & 3;      // component d = 4c + j = t
    float s = 0.f;
#pragma unroll
    for (int m = 0; m < 64; m++) s += red[(c + 4 * m) * 4 + j];
    partial[((size_t)b * BLK_PER_B + blk) * 16 + t] = s;
  }
}

// ---------------------------------------------------------------------------
// k2: single block -> comb[8][16] (fp32)
// partial is [8][128][16] flat = 16384 floats.
// ---------------------------------------------------------------------------
__global__ __launch_bounds__(256) void k2_small(
    const float* __restrict__ partial,   // [8*128*16]
    const float* __restrict__ ctrl,      // [8,4]
    const float* __restrict__ rulemem,   // [8,8,16]
    const float* __restrict__ templates, // [8,16]
    const float* __restrict__ W1,        // [9,64]
    const float* __restrict__ b1,        // [64]
    const float* __restrict__ W2,        // [64,8]
    const float* __restrict__ b2,        // [8]
    const float* __restrict__ Wr,        // [16,128]
    const float* __restrict__ br,        // [128]
    const float* __restrict__ logt,     // [1]
    float* __restrict__ comb) {
  const int t = threadIdx.x;
  __shared__ float summary[8][16], rs[8][16], gn[8][5], h[8][64], sc[8][8];
  __shared__ float instr[8][8][16], g64[64], wts[8][8];
  __shared__ float redA[8][16][16];      // [b][seg][d]

  // A: cooperative load+reduce of partial.
  // flat idx = c*256 + t: b = c>>3 (exact: (c%8)*256+t < 2048), d = t&15.
  {
    float acc[8];
#pragma unroll
    for (int q = 0; q < 8; q++) acc[q] = 0.f;
#pragma unroll
    for (int c = 0; c < 64; c++)
      acc[c >> 3] += partial[c * 256 + t];   // 64 coalesced, independent loads
#pragma unroll
    for (int q = 0; q < 8; q++) redA[q][t >> 4][t & 15] = acc[q];
  }
  // rule summary + gumbel (no dependency on partial)
  if (t < 128) {
    const int bb = t >> 4, d = t & 15;
    float rsum = 0.f;
    for (int m = 0; m < M_; m++) rsum += rulemem[(bb * M_ + m) * 16 + d];
    rs[bb][d] = rsum * (1.0f / (float)M_);
  }
  if (t < 64) {   // partitionable threefry gumbel: counter (0, t), key (0, 42)
    unsigned x0 = 0u, x1 = (unsigned)t;
    threefry2x32(0u, 42u, x0, x1);
    unsigned bits = x0 ^ x1;
    float f01 = __uint_as_float((bits >> 9) | 0x3f800000u) - 1.0f;
    float u = fmaxf(1e-6f, f01 * (1.0f - 2e-6f) + 1e-6f);
    g64[t] = -logf(-logf(u));
  }
  __syncthreads();
  if (t < 128) {
    const int bb = t >> 4, d = t & 15;
    float s = 0.f;
#pragma unroll
    for (int g = 0; g < 16; g++) s += redA[bb][g][d];
    summary[bb][d] = s * (1.0f / (float)N_);
  }
  __syncthreads();
  // B: grade norms
  if (t < 40) {
    const int bb = t / 5, g = t % 5;
    float s = 0.f;
    for (int d = 0; d < 16; d++)
      if (__popc(d) == g) { float v = summary[bb][d]; s += v * v; }
    gn[bb][g] = sqrtf(s + 1e-12f);
  }
  __syncthreads();
  // C1: hidden layer [8][64]
  for (int idx = t; idx < B_ * HID_; idx += 256) {
    const int bb = idx >> 6, j = idx & 63;
    float a = b1[j];
    for (int i = 0; i < 9; i++) {
      float in = (i < 5) ? gn[bb][i] : ctrl[bb * 4 + (i - 5)];
      a += in * W1[i * HID_ + j];
    }
    h[bb][j] = fmaxf(a, 0.f);
  }
  __syncthreads();
  // C2: scores [8][8]
  if (t < 64) {
    const int bb = t >> 3, k = t & 7;
    float a = b2[k];
    for (int j = 0; j < HID_; j++) a += h[bb][j] * W2[j * K_ + k];
    sc[bb][k] = a;
  }
  __syncthreads();
  // D: instructions [8][8][16] = scores * (templates + rule_mod)
  for (int idx = t; idx < B_ * K_ * 16; idx += 256) {
    const int bb = idx >> 7, k = (idx >> 4) & 7, d = idx & 15;
    float a = br[k * 16 + d];
    for (int j = 0; j < 16; j++) a += rs[bb][j] * Wr[j * 128 + k * 16 + d];
    instr[bb][k][d] = sc[bb][k] * (templates[k * 16 + d] + a);
  }
  // weights: softmax((scores+g)/tau)
  if (t < 8) {
    float lt = logt[0];
    float tau = fminf(fmaxf(expf(lt), 0.1f), 5.0f);
    float z[8], m = -1e30f;
    for (int k = 0; k < 8; k++) {
      z[k] = (sc[t][k] + g64[t * 8 + k]) / tau;
      m = fmaxf(m, z[k]);
    }
    float ssum = 0.f;
    for (int k = 0; k < 8; k++) { z[k] = expf(z[k] - m); ssum += z[k]; }
    for (int k = 0; k < 8; k++) wts[t][k] = z[k] / ssum;
  }
  __syncthreads();
  // F: comb[b][i] = sum_k w * instr
  if (t < 128) {
    const int bb = t >> 4, i = t & 15;
    float s = 0.f;
    for (int k = 0; k < 8; k++) s += wts[bb][k] * instr[bb][k][i];
    comb[bb * 16 + i] = s;
  }
}

// ---------------------------------------------------------------------------
// k3: out[b,n,l] = sum_j x[b,n,j] * comb[b][j^l] * SGN[j^l][j]
// grid 2048 blocks x 256 threads, 1 row/thread (4x float4 in, 4x float4 out)
// ---------------------------------------------------------------------------
__global__ __launch_bounds__(256) void k3_apply(
    const float* __restrict__ cpu, const float* __restrict__ comb,
    float* __restrict__ out) {
  const int b = blockIdx.x >> 8;                       // wave-uniform
  const int rowInB = ((blockIdx.x & 255) << 8) + threadIdx.x;
  const size_t row = ((size_t)b << 16) + (size_t)rowInB;

  float cb[16];
  const float* cp = comb + b * 16;
#pragma unroll
  for (int i = 0; i < 16; i++) cb[i] = cp[i];          // uniform -> s_load

  const float4* p = (const float4*)(cpu + row * D_);
  float4 v0 = p[0], v1 = p[1], v2 = p[2], v3 = p[3];
  float x[16] = {v0.x, v0.y, v0.z, v0.w, v1.x, v1.y, v1.z, v1.w,
                 v2.x, v2.y, v2.z, v2.w, v3.x, v3.y, v3.z, v3.w};

  float o[16];
  apply_row(cb, x, o);

  float4* q = (float4*)(out + row * D_);
  q[0] = make_float4(o[0],  o[1],  o[2],  o[3]);
  q[1] = make_float4(o[4],  o[5],  o[6],  o[7]);
  q[2] = make_float4(o[8],  o[9],  o[10], o[11]);
  q[3] = make_float4(o[12], o[13], o[14], o[15]);
}

extern "C" void kernel_launch(void* const* d_in, const int* in_sizes, int n_in,
                              void* d_out, int out_size, void* d_ws, size_t ws_size,
                              hipStream_t stream) {
  const float* cpu       = (const float*)d_in[0];
  const float* ctrl      = (const float*)d_in[1];
  const float* rulemem   = (const float*)d_in[2];
  const float* templates = (const float*)d_in[3];
  const float* W1        = (const float*)d_in[4];
  const float* b1        = (const float*)d_in[5];
  const float* W2        = (const float*)d_in[6];
  const float* b2        = (const float*)d_in[7];
  const float* Wr        = (const float*)d_in[8];
  const float* br        = (const float*)d_in[9];
  const float* logt      = (const float*)d_in[10];
  float* outp = (float*)d_out;

  // partial: 8*128*16 floats (64 KiB) + comb: 128 floats.
  float* partial = (float*)d_ws;
  float* comb;
  const size_t need = (size_t)(B_ * BLK_PER_B * 16 + B_ * 16) * sizeof(float);
  if (ws_size >= need) {
    comb = partial + (size_t)B_ * BLK_PER_B * 16;
  } else {
    // stage partial in the output buffer (fully consumed by k2 before k3's
    // first store; regions separated by kernel boundaries)
    partial = outp;
    comb = (float*)d_ws;
  }

  k1_reduce<<<dim3(BLK_PER_B, B_), 256, 0, stream>>>(cpu, partial);
  k2_small<<<1, 256, 0, stream>>>(partial, ctrl, rulemem, templates, W1, b1,
                                  W2, b2, Wr, br, logt, comb);
  k3_apply<<<2048, 256, 0, stream>>>(cpu, comb, outp);
}